// Round 6
// baseline (258.371 us; speedup 1.0000x reference)
//
#include <hip/hip_runtime.h>
#include <hip/hip_bf16.h>
#include <math.h>

#define NB 16384
#define MED 1000
#define MD 100000          // diag table rows
#define MP 50000           // proc table rows
#define TDBLK 782          // ceil(100000/128)
#define TPBLK 391          // ceil(50000/128)
#define NTR (TDBLK + TPBLK)
#define NCV 1280           // convert blocks: (65536+262144)/256
#define FP8_SCALE 4096.0f
#define FP8_INV   (1.0f / 4096.0f)

typedef __bf16 bf16x8 __attribute__((ext_vector_type(8)));
typedef float  f32x4  __attribute__((ext_vector_type(4)));
typedef float  f32x2  __attribute__((ext_vector_type(2)));
typedef unsigned short u16;
typedef unsigned int   u32;
typedef unsigned char  u8;

__device__ __forceinline__ u16 f2bf(float f) {
    union { float f; u32 u; } v; v.f = f;
    u32 r = v.u + 0x7fffu + ((v.u >> 16) & 1u);   // RNE
    return (u16)(r >> 16);
}

// ---------------------------------------------------------------------------
// prep: (a) transform tables  T_d = fp8( E_d @ W1[:, :128]^T * 4096 ),
//                             T_p = fp8( E_p @ W1[:, 128:]^T * 4096 )
//       (b) convert W2, W3 -> bf16 (W3 zero-padded to 1024 rows)
// ---------------------------------------------------------------------------
__global__ __launch_bounds__(256) void prep_kernel(
    const float* __restrict__ Ed, const float* __restrict__ Ep,
    const float* __restrict__ W1,
    const float* __restrict__ W2, const float* __restrict__ W3,
    u8* __restrict__ Td, u8* __restrict__ Tp,
    u16* __restrict__ W2b, u16* __restrict__ W3b)
{
    __shared__ u16 w1s[128 * 132];     // [out 128][k 128] bf16, stride 132
    const int bid = blockIdx.x, tid = threadIdx.x;

    if (bid >= NTR) {                   // ---- weight convert blocks ----
        int i = (bid - NTR) * 256 + tid;
        if (i < 65536) { W2b[i] = f2bf(W2[i]); return; }
        i -= 65536;
        if (i < 262144) W3b[i] = (i < MED * 256) ? f2bf(W3[i]) : (u16)0;
        return;
    }

    int blk = bid;
    const float* E; u8* T; int M, koff;
    if (blk < TDBLK) { E = Ed; T = Td; M = MD; koff = 0; }
    else             { blk -= TDBLK; E = Ep; T = Tp; M = MP; koff = 128; }

    // stage W1[:, koff:koff+128] bf16 into LDS
    for (int idx = tid; idx < 4096; idx += 256) {     // 4096 float4s
        const int row = idx >> 5, c4 = idx & 31;
        const float4 v = *(const float4*)(W1 + row * 256 + koff + c4 * 4);
        u16* d = &w1s[row * 132 + c4 * 4];
        d[0] = f2bf(v.x); d[1] = f2bf(v.y); d[2] = f2bf(v.z); d[3] = f2bf(v.w);
    }
    __syncthreads();

    const int wave = tid >> 6, lane = tid & 63;
    const int quad = lane >> 4, l16 = lane & 15;
    const int n0 = blk * 128 + wave * 32;
    const float* bP0 = E + (size_t)min(n0 + l16,      M - 1) * 128 + quad * 8;
    const float* bP1 = E + (size_t)min(n0 + 16 + l16, M - 1) * 128 + quad * 8;

    f32x4 acc[8][2];
    #pragma unroll
    for (int mt = 0; mt < 8; ++mt) {
        acc[mt][0] = (f32x4){0.f,0.f,0.f,0.f};
        acc[mt][1] = (f32x4){0.f,0.f,0.f,0.f};
    }

    #pragma unroll
    for (int ks = 0; ks < 4; ++ks) {
        union { bf16x8 v; u16 s[8]; } b0, b1;
        const float4 f0 = *(const float4*)(bP0 + ks * 32);
        const float4 f1 = *(const float4*)(bP0 + ks * 32 + 4);
        const float4 g0 = *(const float4*)(bP1 + ks * 32);
        const float4 g1 = *(const float4*)(bP1 + ks * 32 + 4);
        b0.s[0]=f2bf(f0.x); b0.s[1]=f2bf(f0.y); b0.s[2]=f2bf(f0.z); b0.s[3]=f2bf(f0.w);
        b0.s[4]=f2bf(f1.x); b0.s[5]=f2bf(f1.y); b0.s[6]=f2bf(f1.z); b0.s[7]=f2bf(f1.w);
        b1.s[0]=f2bf(g0.x); b1.s[1]=f2bf(g0.y); b1.s[2]=f2bf(g0.z); b1.s[3]=f2bf(g0.w);
        b1.s[4]=f2bf(g1.x); b1.s[5]=f2bf(g1.y); b1.s[6]=f2bf(g1.z); b1.s[7]=f2bf(g1.w);
        #pragma unroll
        for (int mt = 0; mt < 8; ++mt) {
            const bf16x8 a = *(const bf16x8*)&w1s[(mt * 16 + l16) * 132 + ks * 32 + quad * 8];
            acc[mt][0] = __builtin_amdgcn_mfma_f32_16x16x32_bf16(a, b0.v, acc[mt][0], 0, 0, 0);
            acc[mt][1] = __builtin_amdgcn_mfma_f32_16x16x32_bf16(a, b1.v, acc[mt][1], 0, 0, 0);
        }
    }

    #pragma unroll
    for (int nt = 0; nt < 2; ++nt) {
        const int rn = n0 + nt * 16 + l16;
        if (rn < M) {
            u8* rowp = T + (size_t)rn * 128 + quad * 4;
            #pragma unroll
            for (int mt = 0; mt < 8; ++mt) {
                const f32x4 a = acc[mt][nt];
                int p = __builtin_amdgcn_cvt_pk_fp8_f32(a[0] * FP8_SCALE, a[1] * FP8_SCALE, 0, 0);
                p = __builtin_amdgcn_cvt_pk_fp8_f32(a[2] * FP8_SCALE, a[3] * FP8_SCALE, p, 1);
                *(u32*)(rowp + mt * 16) = (u32)p;
            }
        }
    }
}

// ---------------------------------------------------------------------------
// Gather+sum from fp8 tables -> rep (cur|prev, rescale + b1 folded).
// Block = 8 batch rows; t = sub(3b)|bag(2b)|lc(3b); thread = 16 B x 32 rows
// (uint4 loads: half the VMEM requests of the R5 uint2 version).
// ---------------------------------------------------------------------------
__global__ __launch_bounds__(256) void gather_rep(
    const int* __restrict__ diag, const int* __restrict__ proc,
    const int* __restrict__ pdiag, const int* __restrict__ pproc,
    const u8* __restrict__ Td, const u8* __restrict__ Tp,
    const float* __restrict__ b1, u16* __restrict__ rep)
{
    __shared__ int   sidx[8 * 4 * 33];       // [sub][bag][33]
    __shared__ float sred[8][2][8][16];      // [sub][half][lc][16] = 16 KB
    const int t = threadIdx.x;

    for (int i = t; i < 1024; i += 256) {
        const int s = i >> 7, bg = (i >> 5) & 3, l = i & 31;
        const int* cp = (bg == 0) ? diag : (bg == 1) ? proc : (bg == 2) ? pdiag : pproc;
        sidx[(s * 4 + bg) * 33 + l] = cp[(blockIdx.x * 8 + s) * 32 + l];
    }
    __syncthreads();

    const int sub = t >> 5, bag = (t >> 3) & 3, lc = t & 7;
    const u8* tbl = (bag & 1) ? Tp : Td;
    const int* myidx = &sidx[(sub * 4 + bag) * 33];

    f32x2 s[8];
    #pragma unroll
    for (int i = 0; i < 8; ++i) s[i] = (f32x2){0.f, 0.f};

    uint4 va[8], vb[8];
    #pragma unroll
    for (int j = 0; j < 8; ++j)
        va[j] = *(const uint4*)(tbl + (size_t)myidx[j] * 128 + lc * 16);
    #pragma unroll
    for (int j = 0; j < 8; ++j)
        vb[j] = *(const uint4*)(tbl + (size_t)myidx[8 + j] * 128 + lc * 16);

#define CONSUME(V) do { \
    _Pragma("unroll") \
    for (int j = 0; j < 8; ++j) { \
        s[0] += __builtin_amdgcn_cvt_pk_f32_fp8((int)V[j].x, 0); \
        s[1] += __builtin_amdgcn_cvt_pk_f32_fp8((int)V[j].x, 1); \
        s[2] += __builtin_amdgcn_cvt_pk_f32_fp8((int)V[j].y, 0); \
        s[3] += __builtin_amdgcn_cvt_pk_f32_fp8((int)V[j].y, 1); \
        s[4] += __builtin_amdgcn_cvt_pk_f32_fp8((int)V[j].z, 0); \
        s[5] += __builtin_amdgcn_cvt_pk_f32_fp8((int)V[j].z, 1); \
        s[6] += __builtin_amdgcn_cvt_pk_f32_fp8((int)V[j].w, 0); \
        s[7] += __builtin_amdgcn_cvt_pk_f32_fp8((int)V[j].w, 1); \
    } } while (0)

    {
        uint4 tmp[8];
        #pragma unroll
        for (int j = 0; j < 8; ++j)
            tmp[j] = *(const uint4*)(tbl + (size_t)myidx[16 + j] * 128 + lc * 16);
        CONSUME(va);
        #pragma unroll
        for (int j = 0; j < 8; ++j) va[j] = tmp[j];
    }
    {
        uint4 tmp[8];
        #pragma unroll
        for (int j = 0; j < 8; ++j)
            tmp[j] = *(const uint4*)(tbl + (size_t)myidx[24 + j] * 128 + lc * 16);
        CONSUME(vb);
        #pragma unroll
        for (int j = 0; j < 8; ++j) vb[j] = tmp[j];
    }
    CONSUME(va);
    CONSUME(vb);
#undef CONSUME

    const int half = bag >> 1;
    if (bag & 1) {
        float* dst = &sred[sub][half][lc][0];
        #pragma unroll
        for (int i = 0; i < 4; ++i)
            *(f32x4*)(dst + i * 4) = (f32x4){s[2*i].x, s[2*i].y, s[2*i+1].x, s[2*i+1].y};
    }
    __syncthreads();
    if (!(bag & 1)) {
        const float* par = &sred[sub][half][lc][0];
        const float* bp  = b1 + lc * 16;
        u32 o[8];
        #pragma unroll
        for (int i = 0; i < 8; ++i) {
            const float e0 = (s[i].x + par[2*i])   * FP8_INV + bp[2*i];
            const float e1 = (s[i].y + par[2*i+1]) * FP8_INV + bp[2*i+1];
            o[i] = (u32)f2bf(e0) | ((u32)f2bf(e1) << 16);
        }
        const int b = blockIdx.x * 8 + sub;
        u16* dst = rep + (size_t)b * 256 + half * 128 + lc * 16;
        *(uint4*)dst       = make_uint4(o[0], o[1], o[2], o[3]);
        *(uint4*)(dst + 8) = make_uint4(o[4], o[5], o[6], o[7]);
    }
}

// ---------------------------------------------------------------------------
// GEMM2: h = relu(rep @ W2^T + b2), bf16 out. Block M=32, grid 512.
// Wave tile 32x64. Explicit 1-deep register ping-pong prefetch of the next
// K-step's 6 loads so MFMAs overlap the L2 latency.
// ---------------------------------------------------------------------------
__global__ __launch_bounds__(256) void gemm2(
    const u16* __restrict__ rep, const u16* __restrict__ W2b,
    const float* __restrict__ b2, u16* __restrict__ h)
{
    const int wave = threadIdx.x >> 6, lane = threadIdx.x & 63;
    const int quad = lane >> 4, l16 = lane & 15;
    const int mBase = blockIdx.x * 32;
    const int nBase = wave * 64;
    const u16* aP0 = rep + (size_t)(mBase + l16) * 256 + quad * 8;
    const u16* aP1 = aP0 + 16 * 256;
    const u16* wP  = W2b + (size_t)(nBase + l16) * 256 + quad * 8;

    f32x4 acc[2][4];
    #pragma unroll
    for (int mt = 0; mt < 2; ++mt)
        #pragma unroll
        for (int nt = 0; nt < 4; ++nt) acc[mt][nt] = (f32x4){0.f,0.f,0.f,0.f};

    bf16x8 a0 = *(const bf16x8*)(aP0);
    bf16x8 a1 = *(const bf16x8*)(aP1);
    bf16x8 b[4];
    #pragma unroll
    for (int nt = 0; nt < 4; ++nt) b[nt] = *(const bf16x8*)(wP + nt * 4096);

    #pragma unroll
    for (int ks = 0; ks < 8; ++ks) {
        bf16x8 a0n = a0, a1n = a1, bn[4];
        #pragma unroll
        for (int nt = 0; nt < 4; ++nt) bn[nt] = b[nt];
        if (ks < 7) {
            a0n = *(const bf16x8*)(aP0 + (ks + 1) * 32);
            a1n = *(const bf16x8*)(aP1 + (ks + 1) * 32);
            #pragma unroll
            for (int nt = 0; nt < 4; ++nt)
                bn[nt] = *(const bf16x8*)(wP + nt * 4096 + (ks + 1) * 32);
        }
        #pragma unroll
        for (int nt = 0; nt < 4; ++nt) {
            acc[0][nt] = __builtin_amdgcn_mfma_f32_16x16x32_bf16(a0, b[nt], acc[0][nt], 0, 0, 0);
            acc[1][nt] = __builtin_amdgcn_mfma_f32_16x16x32_bf16(a1, b[nt], acc[1][nt], 0, 0, 0);
        }
        a0 = a0n; a1 = a1n;
        #pragma unroll
        for (int nt = 0; nt < 4; ++nt) b[nt] = bn[nt];
    }

    #pragma unroll
    for (int mt = 0; mt < 2; ++mt) {
        const int rowB = mBase + mt * 16 + quad * 4;
        #pragma unroll
        for (int nt = 0; nt < 4; ++nt) {
            const int col = nBase + nt * 16 + l16;
            const float bv = b2[col];
            #pragma unroll
            for (int r = 0; r < 4; ++r) {
                float v = acc[mt][nt][r] + bv;
                v = v > 0.f ? v : 0.f;
                h[(size_t)(rowB + r) * 256 + col] = f2bf(v);
            }
        }
    }
}

// ---------------------------------------------------------------------------
// GEMM3: out = sigmoid(h @ W3^T + b3), fp32 out [16384,1000].
// Block 64x128, grid (256, 8). Wave tile 32x64, explicit ping-pong prefetch,
// sigmoid via v_exp + v_rcp.
// ---------------------------------------------------------------------------
__global__ __launch_bounds__(256) void gemm3(
    const u16* __restrict__ h, const u16* __restrict__ W3b,
    const float* __restrict__ b3, float* __restrict__ out)
{
    const int wave = threadIdx.x >> 6, lane = threadIdx.x & 63;
    const int quad = lane >> 4, l16 = lane & 15;
    const int mBase = blockIdx.x * 64 + (wave & 1) * 32;
    const int nBase = blockIdx.y * 128 + (wave >> 1) * 64;
    const u16* aP0 = h + (size_t)(mBase + l16) * 256 + quad * 8;
    const u16* aP1 = aP0 + 16 * 256;
    const u16* wP  = W3b + (size_t)(nBase + l16) * 256 + quad * 8;

    f32x4 acc[2][4];
    #pragma unroll
    for (int mt = 0; mt < 2; ++mt)
        #pragma unroll
        for (int nt = 0; nt < 4; ++nt) acc[mt][nt] = (f32x4){0.f,0.f,0.f,0.f};

    bf16x8 a0 = *(const bf16x8*)(aP0);
    bf16x8 a1 = *(const bf16x8*)(aP1);
    bf16x8 b[4];
    #pragma unroll
    for (int nt = 0; nt < 4; ++nt) b[nt] = *(const bf16x8*)(wP + nt * 4096);

    #pragma unroll
    for (int ks = 0; ks < 8; ++ks) {
        bf16x8 a0n = a0, a1n = a1, bn[4];
        #pragma unroll
        for (int nt = 0; nt < 4; ++nt) bn[nt] = b[nt];
        if (ks < 7) {
            a0n = *(const bf16x8*)(aP0 + (ks + 1) * 32);
            a1n = *(const bf16x8*)(aP1 + (ks + 1) * 32);
            #pragma unroll
            for (int nt = 0; nt < 4; ++nt)
                bn[nt] = *(const bf16x8*)(wP + nt * 4096 + (ks + 1) * 32);
        }
        #pragma unroll
        for (int nt = 0; nt < 4; ++nt) {
            acc[0][nt] = __builtin_amdgcn_mfma_f32_16x16x32_bf16(a0, b[nt], acc[0][nt], 0, 0, 0);
            acc[1][nt] = __builtin_amdgcn_mfma_f32_16x16x32_bf16(a1, b[nt], acc[1][nt], 0, 0, 0);
        }
        a0 = a0n; a1 = a1n;
        #pragma unroll
        for (int nt = 0; nt < 4; ++nt) b[nt] = bn[nt];
    }

    #pragma unroll
    for (int nt = 0; nt < 4; ++nt) {
        const int col = nBase + nt * 16 + l16;
        if (col < MED) {
            const float bv = b3[col];
            #pragma unroll
            for (int mt = 0; mt < 2; ++mt) {
                const int rowB = mBase + mt * 16 + quad * 4;
                #pragma unroll
                for (int r = 0; r < 4; ++r) {
                    const float v = acc[mt][nt][r] + bv;
                    const float e = __expf(-v);
                    out[(size_t)(rowB + r) * MED + col] = __builtin_amdgcn_rcpf(1.0f + e);
                }
            }
        }
    }
}

// ---------------------------------------------------------------------------
extern "C" void kernel_launch(void* const* d_in, const int* in_sizes, int n_in,
                              void* d_out, int out_size, void* d_ws, size_t ws_size,
                              hipStream_t stream)
{
    const int*   diag  = (const int*)d_in[0];
    const int*   proc  = (const int*)d_in[1];
    const int*   pdiag = (const int*)d_in[2];
    const int*   pproc = (const int*)d_in[3];
    const float* demb  = (const float*)d_in[4];
    const float* pemb  = (const float*)d_in[5];
    const float* W1    = (const float*)d_in[6];
    const float* b1    = (const float*)d_in[7];
    const float* W2    = (const float*)d_in[8];
    const float* b2    = (const float*)d_in[9];
    const float* W3    = (const float*)d_in[10];
    const float* b3    = (const float*)d_in[11];

    char* ws = (char*)d_ws;
    // ws layout (bytes), total ~28.2 MB:
    //   Td  [100000,128] fp8  : 0          .. 12,800,000   (h aliases Td after gather)
    //   Tp  [ 50000,128] fp8  : 12,800,000 .. 19,200,000
    //   rep [16384,256]  bf16 : 19,200,000 .. 27,588,608
    //   W2b [256,256]    bf16 : 27,588,608 .. 27,719,680
    //   W3b [1024,256]   bf16 : 27,719,680 .. 28,243,968
    u8*  Td  = (u8*)ws;
    u8*  Tp  = (u8*)(ws + 12800000);
    u16* rep = (u16*)(ws + 19200000);
    u16* W2b = (u16*)(ws + 27588608);
    u16* W3b = (u16*)(ws + 27719680);
    u16* h   = (u16*)ws;               // aliases Td (dead after gather_rep)

    prep_kernel<<<NTR + NCV, 256, 0, stream>>>(demb, pemb, W1, W2, W3, Td, Tp, W2b, W3b);
    gather_rep<<<NB / 8, 256, 0, stream>>>(diag, proc, pdiag, pproc, Td, Tp, b1, rep);
    gemm2<<<512, 256, 0, stream>>>(rep, W2b, b2, h);
    gemm3<<<dim3(256, 8), 256, 0, stream>>>(h, W3b, b3, (float*)d_out);
}

// Round 7
// 241.525 us; speedup vs baseline: 1.0697x; 1.0697x over previous
//
#include <hip/hip_runtime.h>
#include <hip/hip_bf16.h>
#include <math.h>

#define NB 16384
#define MED 1000
#define MD 100000          // diag table rows
#define MP 50000           // proc table rows
#define TDBLK 782          // ceil(100000/128)
#define TPBLK 391          // ceil(50000/128)
#define NTR (TDBLK + TPBLK)
#define NCV 1280           // convert blocks: (65536+262144)/256
#define FP8_SCALE 4096.0f
#define FP8_INV   (1.0f / 4096.0f)

typedef __bf16 bf16x8 __attribute__((ext_vector_type(8)));
typedef float  f32x4  __attribute__((ext_vector_type(4)));
typedef float  f32x2  __attribute__((ext_vector_type(2)));
typedef unsigned short u16;
typedef unsigned int   u32;
typedef unsigned char  u8;

__device__ __forceinline__ u16 f2bf(float f) {
    union { float f; u32 u; } v; v.f = f;
    u32 r = v.u + 0x7fffu + ((v.u >> 16) & 1u);   // RNE
    return (u16)(r >> 16);
}

// ---------------------------------------------------------------------------
// prep: (a) transform tables  T_d = fp8( E_d @ W1[:, :128]^T * 4096 ),
//                             T_p = fp8( E_p @ W1[:, 128:]^T * 4096 )
//       (b) convert W2, W3 -> bf16 (W3 zero-padded to 1024 rows)
// ---------------------------------------------------------------------------
__global__ __launch_bounds__(256) void prep_kernel(
    const float* __restrict__ Ed, const float* __restrict__ Ep,
    const float* __restrict__ W1,
    const float* __restrict__ W2, const float* __restrict__ W3,
    u8* __restrict__ Td, u8* __restrict__ Tp,
    u16* __restrict__ W2b, u16* __restrict__ W3b)
{
    __shared__ u16 w1s[128 * 132];     // [out 128][k 128] bf16, stride 132
    const int bid = blockIdx.x, tid = threadIdx.x;

    if (bid >= NTR) {                   // ---- weight convert blocks ----
        int i = (bid - NTR) * 256 + tid;
        if (i < 65536) { W2b[i] = f2bf(W2[i]); return; }
        i -= 65536;
        if (i < 262144) W3b[i] = (i < MED * 256) ? f2bf(W3[i]) : (u16)0;
        return;
    }

    int blk = bid;
    const float* E; u8* T; int M, koff;
    if (blk < TDBLK) { E = Ed; T = Td; M = MD; koff = 0; }
    else             { blk -= TDBLK; E = Ep; T = Tp; M = MP; koff = 128; }

    // stage W1[:, koff:koff+128] bf16 into LDS
    for (int idx = tid; idx < 4096; idx += 256) {     // 4096 float4s
        const int row = idx >> 5, c4 = idx & 31;
        const float4 v = *(const float4*)(W1 + row * 256 + koff + c4 * 4);
        u16* d = &w1s[row * 132 + c4 * 4];
        d[0] = f2bf(v.x); d[1] = f2bf(v.y); d[2] = f2bf(v.z); d[3] = f2bf(v.w);
    }
    __syncthreads();

    const int wave = tid >> 6, lane = tid & 63;
    const int quad = lane >> 4, l16 = lane & 15;
    const int n0 = blk * 128 + wave * 32;
    const float* bP0 = E + (size_t)min(n0 + l16,      M - 1) * 128 + quad * 8;
    const float* bP1 = E + (size_t)min(n0 + 16 + l16, M - 1) * 128 + quad * 8;

    f32x4 acc[8][2];
    #pragma unroll
    for (int mt = 0; mt < 8; ++mt) {
        acc[mt][0] = (f32x4){0.f,0.f,0.f,0.f};
        acc[mt][1] = (f32x4){0.f,0.f,0.f,0.f};
    }

    #pragma unroll
    for (int ks = 0; ks < 4; ++ks) {
        union { bf16x8 v; u16 s[8]; } b0, b1;
        const float4 f0 = *(const float4*)(bP0 + ks * 32);
        const float4 f1 = *(const float4*)(bP0 + ks * 32 + 4);
        const float4 g0 = *(const float4*)(bP1 + ks * 32);
        const float4 g1 = *(const float4*)(bP1 + ks * 32 + 4);
        b0.s[0]=f2bf(f0.x); b0.s[1]=f2bf(f0.y); b0.s[2]=f2bf(f0.z); b0.s[3]=f2bf(f0.w);
        b0.s[4]=f2bf(f1.x); b0.s[5]=f2bf(f1.y); b0.s[6]=f2bf(f1.z); b0.s[7]=f2bf(f1.w);
        b1.s[0]=f2bf(g0.x); b1.s[1]=f2bf(g0.y); b1.s[2]=f2bf(g0.z); b1.s[3]=f2bf(g0.w);
        b1.s[4]=f2bf(g1.x); b1.s[5]=f2bf(g1.y); b1.s[6]=f2bf(g1.z); b1.s[7]=f2bf(g1.w);
        #pragma unroll
        for (int mt = 0; mt < 8; ++mt) {
            const bf16x8 a = *(const bf16x8*)&w1s[(mt * 16 + l16) * 132 + ks * 32 + quad * 8];
            acc[mt][0] = __builtin_amdgcn_mfma_f32_16x16x32_bf16(a, b0.v, acc[mt][0], 0, 0, 0);
            acc[mt][1] = __builtin_amdgcn_mfma_f32_16x16x32_bf16(a, b1.v, acc[mt][1], 0, 0, 0);
        }
    }

    #pragma unroll
    for (int nt = 0; nt < 2; ++nt) {
        const int rn = n0 + nt * 16 + l16;
        if (rn < M) {
            u8* rowp = T + (size_t)rn * 128 + quad * 4;
            #pragma unroll
            for (int mt = 0; mt < 8; ++mt) {
                const f32x4 a = acc[mt][nt];
                int p = __builtin_amdgcn_cvt_pk_fp8_f32(a[0] * FP8_SCALE, a[1] * FP8_SCALE, 0, 0);
                p = __builtin_amdgcn_cvt_pk_fp8_f32(a[2] * FP8_SCALE, a[3] * FP8_SCALE, p, 1);
                *(u32*)(rowp + mt * 16) = (u32)p;
            }
        }
    }
}

// ---------------------------------------------------------------------------
// Gather+sum from fp8 tables -> rep (cur|prev, rescale + b1 folded).
// Block = 8 batch rows; t = sub(3b)|bag(2b)|lc(3b); thread = 16 B x 32 rows.
// ---------------------------------------------------------------------------
__global__ __launch_bounds__(256) void gather_rep(
    const int* __restrict__ diag, const int* __restrict__ proc,
    const int* __restrict__ pdiag, const int* __restrict__ pproc,
    const u8* __restrict__ Td, const u8* __restrict__ Tp,
    const float* __restrict__ b1, u16* __restrict__ rep)
{
    __shared__ int   sidx[8 * 4 * 33];       // [sub][bag][33]
    __shared__ float sred[8][2][8][16];      // [sub][half][lc][16] = 16 KB
    const int t = threadIdx.x;

    for (int i = t; i < 1024; i += 256) {
        const int s = i >> 7, bg = (i >> 5) & 3, l = i & 31;
        const int* cp = (bg == 0) ? diag : (bg == 1) ? proc : (bg == 2) ? pdiag : pproc;
        sidx[(s * 4 + bg) * 33 + l] = cp[(blockIdx.x * 8 + s) * 32 + l];
    }
    __syncthreads();

    const int sub = t >> 5, bag = (t >> 3) & 3, lc = t & 7;
    const u8* tbl = (bag & 1) ? Tp : Td;
    const int* myidx = &sidx[(sub * 4 + bag) * 33];

    f32x2 s[8];
    #pragma unroll
    for (int i = 0; i < 8; ++i) s[i] = (f32x2){0.f, 0.f};

    uint4 va[8], vb[8];
    #pragma unroll
    for (int j = 0; j < 8; ++j)
        va[j] = *(const uint4*)(tbl + (size_t)myidx[j] * 128 + lc * 16);
    #pragma unroll
    for (int j = 0; j < 8; ++j)
        vb[j] = *(const uint4*)(tbl + (size_t)myidx[8 + j] * 128 + lc * 16);

#define CONSUME(V) do { \
    _Pragma("unroll") \
    for (int j = 0; j < 8; ++j) { \
        s[0] += __builtin_amdgcn_cvt_pk_f32_fp8((int)V[j].x, 0); \
        s[1] += __builtin_amdgcn_cvt_pk_f32_fp8((int)V[j].x, 1); \
        s[2] += __builtin_amdgcn_cvt_pk_f32_fp8((int)V[j].y, 0); \
        s[3] += __builtin_amdgcn_cvt_pk_f32_fp8((int)V[j].y, 1); \
        s[4] += __builtin_amdgcn_cvt_pk_f32_fp8((int)V[j].z, 0); \
        s[5] += __builtin_amdgcn_cvt_pk_f32_fp8((int)V[j].z, 1); \
        s[6] += __builtin_amdgcn_cvt_pk_f32_fp8((int)V[j].w, 0); \
        s[7] += __builtin_amdgcn_cvt_pk_f32_fp8((int)V[j].w, 1); \
    } } while (0)

    {
        uint4 tmp[8];
        #pragma unroll
        for (int j = 0; j < 8; ++j)
            tmp[j] = *(const uint4*)(tbl + (size_t)myidx[16 + j] * 128 + lc * 16);
        CONSUME(va);
        #pragma unroll
        for (int j = 0; j < 8; ++j) va[j] = tmp[j];
    }
    {
        uint4 tmp[8];
        #pragma unroll
        for (int j = 0; j < 8; ++j)
            tmp[j] = *(const uint4*)(tbl + (size_t)myidx[24 + j] * 128 + lc * 16);
        CONSUME(vb);
        #pragma unroll
        for (int j = 0; j < 8; ++j) vb[j] = tmp[j];
    }
    CONSUME(va);
    CONSUME(vb);
#undef CONSUME

    const int half = bag >> 1;
    if (bag & 1) {
        float* dst = &sred[sub][half][lc][0];
        #pragma unroll
        for (int i = 0; i < 4; ++i)
            *(f32x4*)(dst + i * 4) = (f32x4){s[2*i].x, s[2*i].y, s[2*i+1].x, s[2*i+1].y};
    }
    __syncthreads();
    if (!(bag & 1)) {
        const float* par = &sred[sub][half][lc][0];
        const float* bp  = b1 + lc * 16;
        u32 o[8];
        #pragma unroll
        for (int i = 0; i < 8; ++i) {
            const float e0 = (s[i].x + par[2*i])   * FP8_INV + bp[2*i];
            const float e1 = (s[i].y + par[2*i+1]) * FP8_INV + bp[2*i+1];
            o[i] = (u32)f2bf(e0) | ((u32)f2bf(e1) << 16);
        }
        const int b = blockIdx.x * 8 + sub;
        u16* dst = rep + (size_t)b * 256 + half * 128 + lc * 16;
        *(uint4*)dst       = make_uint4(o[0], o[1], o[2], o[3]);
        *(uint4*)(dst + 8) = make_uint4(o[4], o[5], o[6], o[7]);
    }
}

// ---------------------------------------------------------------------------
// GEMM2: h = relu(rep @ W2^T + b2), bf16 out. W2-resident-in-registers:
// block = 64 N-cols x 128 M-rows, grid (4,128). Wave holds its 64-col W2
// slice (4 n-tiles x 8 k-steps) in VGPRs; 2 M-iterations of 16 rows/wave.
// ---------------------------------------------------------------------------
__global__ __launch_bounds__(256, 2) void gemm2(
    const u16* __restrict__ rep, const u16* __restrict__ W2b,
    const float* __restrict__ b2, u16* __restrict__ h)
{
    const int wave = threadIdx.x >> 6, lane = threadIdx.x & 63;
    const int quad = lane >> 4, l16 = lane & 15;
    const int nBase = blockIdx.x * 64;
    const int mChunk = blockIdx.y * 128;

    bf16x8 w[4][8];
    #pragma unroll
    for (int nt = 0; nt < 4; ++nt) {
        const u16* wP = W2b + (size_t)(nBase + nt * 16 + l16) * 256 + quad * 8;
        #pragma unroll
        for (int ks = 0; ks < 8; ++ks) w[nt][ks] = *(const bf16x8*)(wP + ks * 32);
    }
    float bv[4];
    #pragma unroll
    for (int nt = 0; nt < 4; ++nt) bv[nt] = b2[nBase + nt * 16 + l16];

    const u16* aP = rep + (size_t)(mChunk + wave * 16 + l16) * 256 + quad * 8;
    bf16x8 a[8];
    #pragma unroll
    for (int ks = 0; ks < 8; ++ks) a[ks] = *(const bf16x8*)(aP + ks * 32);

    #pragma unroll 1
    for (int iter = 0; iter < 2; ++iter) {
        bf16x8 an[8];
        if (iter < 1) {
            const u16* aN = aP + 64 * 256;
            #pragma unroll
            for (int ks = 0; ks < 8; ++ks) an[ks] = *(const bf16x8*)(aN + ks * 32);
        }
        f32x4 acc[4];
        #pragma unroll
        for (int nt = 0; nt < 4; ++nt) acc[nt] = (f32x4){0.f,0.f,0.f,0.f};
        #pragma unroll
        for (int ks = 0; ks < 8; ++ks)
            #pragma unroll
            for (int nt = 0; nt < 4; ++nt)
                acc[nt] = __builtin_amdgcn_mfma_f32_16x16x32_bf16(a[ks], w[nt][ks], acc[nt], 0, 0, 0);

        const int rowB = mChunk + iter * 64 + wave * 16 + quad * 4;
        #pragma unroll
        for (int nt = 0; nt < 4; ++nt) {
            const int col = nBase + nt * 16 + l16;
            #pragma unroll
            for (int r = 0; r < 4; ++r) {
                float v = acc[nt][r] + bv[nt];
                v = v > 0.f ? v : 0.f;
                h[(size_t)(rowB + r) * 256 + col] = f2bf(v);
            }
        }
        if (iter < 1) {
            aP += 64 * 256;
            #pragma unroll
            for (int ks = 0; ks < 8; ++ks) a[ks] = an[ks];
        }
    }
}

// ---------------------------------------------------------------------------
// GEMM3: out = sigmoid(h @ W3^T + b3), fp32 [16384,1000]. W3-resident:
// block = 64 N-cols x 512 M-rows, grid (16,32). Wave holds its 64-col W3
// slice in VGPRs (128 regs); 8 M-iterations of 16 rows/wave with the next
// iteration's 8 A-loads issued before the current 32 MFMAs (rolled loop).
// ---------------------------------------------------------------------------
__global__ __launch_bounds__(256, 2) void gemm3(
    const u16* __restrict__ h, const u16* __restrict__ W3b,
    const float* __restrict__ b3, float* __restrict__ out)
{
    const int wave = threadIdx.x >> 6, lane = threadIdx.x & 63;
    const int quad = lane >> 4, l16 = lane & 15;
    const int nBase = blockIdx.x * 64;
    const int mChunk = blockIdx.y * 512;

    bf16x8 w[4][8];
    #pragma unroll
    for (int nt = 0; nt < 4; ++nt) {
        const u16* wP = W3b + (size_t)(nBase + nt * 16 + l16) * 256 + quad * 8;
        #pragma unroll
        for (int ks = 0; ks < 8; ++ks) w[nt][ks] = *(const bf16x8*)(wP + ks * 32);
    }
    float bv[4]; int colv[4];
    #pragma unroll
    for (int nt = 0; nt < 4; ++nt) {
        colv[nt] = nBase + nt * 16 + l16;
        bv[nt] = (colv[nt] < MED) ? b3[colv[nt]] : 0.f;
    }

    const u16* aP = h + (size_t)(mChunk + wave * 16 + l16) * 256 + quad * 8;
    bf16x8 a[8];
    #pragma unroll
    for (int ks = 0; ks < 8; ++ks) a[ks] = *(const bf16x8*)(aP + ks * 32);

    #pragma unroll 1
    for (int iter = 0; iter < 8; ++iter) {
        bf16x8 an[8];
        if (iter < 7) {
            const u16* aN = aP + 64 * 256;
            #pragma unroll
            for (int ks = 0; ks < 8; ++ks) an[ks] = *(const bf16x8*)(aN + ks * 32);
        }
        f32x4 acc[4];
        #pragma unroll
        for (int nt = 0; nt < 4; ++nt) acc[nt] = (f32x4){0.f,0.f,0.f,0.f};
        #pragma unroll
        for (int ks = 0; ks < 8; ++ks)
            #pragma unroll
            for (int nt = 0; nt < 4; ++nt)
                acc[nt] = __builtin_amdgcn_mfma_f32_16x16x32_bf16(a[ks], w[nt][ks], acc[nt], 0, 0, 0);

        const int rowB = mChunk + iter * 64 + wave * 16 + quad * 4;
        #pragma unroll
        for (int nt = 0; nt < 4; ++nt) {
            if (colv[nt] < MED) {
                #pragma unroll
                for (int r = 0; r < 4; ++r) {
                    const float v = acc[nt][r] + bv[nt];
                    const float e = __expf(-v);
                    out[(size_t)(rowB + r) * MED + colv[nt]] = __builtin_amdgcn_rcpf(1.0f + e);
                }
            }
        }
        if (iter < 7) {
            aP += 64 * 256;
            #pragma unroll
            for (int ks = 0; ks < 8; ++ks) a[ks] = an[ks];
        }
    }
}

// ---------------------------------------------------------------------------
extern "C" void kernel_launch(void* const* d_in, const int* in_sizes, int n_in,
                              void* d_out, int out_size, void* d_ws, size_t ws_size,
                              hipStream_t stream)
{
    const int*   diag  = (const int*)d_in[0];
    const int*   proc  = (const int*)d_in[1];
    const int*   pdiag = (const int*)d_in[2];
    const int*   pproc = (const int*)d_in[3];
    const float* demb  = (const float*)d_in[4];
    const float* pemb  = (const float*)d_in[5];
    const float* W1    = (const float*)d_in[6];
    const float* b1    = (const float*)d_in[7];
    const float* W2    = (const float*)d_in[8];
    const float* b2    = (const float*)d_in[9];
    const float* W3    = (const float*)d_in[10];
    const float* b3    = (const float*)d_in[11];

    char* ws = (char*)d_ws;
    // ws layout (bytes), total ~28.2 MB:
    //   Td  [100000,128] fp8  : 0          .. 12,800,000   (h aliases Td after gather)
    //   Tp  [ 50000,128] fp8  : 12,800,000 .. 19,200,000
    //   rep [16384,256]  bf16 : 19,200,000 .. 27,588,608
    //   W2b [256,256]    bf16 : 27,588,608 .. 27,719,680
    //   W3b [1024,256]   bf16 : 27,719,680 .. 28,243,968
    u8*  Td  = (u8*)ws;
    u8*  Tp  = (u8*)(ws + 12800000);
    u16* rep = (u16*)(ws + 19200000);
    u16* W2b = (u16*)(ws + 27588608);
    u16* W3b = (u16*)(ws + 27719680);
    u16* h   = (u16*)ws;               // aliases Td (dead after gather_rep)

    prep_kernel<<<NTR + NCV, 256, 0, stream>>>(demb, pemb, W1, W2, W3, Td, Tp, W2b, W3b);
    gather_rep<<<NB / 8, 256, 0, stream>>>(diag, proc, pdiag, pproc, Td, Tp, b1, rep);
    gemm2<<<dim3(4, 128), 256, 0, stream>>>(rep, W2b, b2, h);
    gemm3<<<dim3(16, 32), 256, 0, stream>>>(h, W3b, b3, (float*)d_out);
}